// Round 15
// baseline (59.583 us; speedup 1.0000x reference)
//
#include <hip/hip_runtime.h>

typedef __bf16 bf16x8 __attribute__((ext_vector_type(8)));
typedef __bf16 bf16x4 __attribute__((ext_vector_type(4)));
typedef float f32x4 __attribute__((ext_vector_type(4)));
typedef float f32x16 __attribute__((ext_vector_type(16)));
typedef unsigned int u32;

#define T_LEN 4096

__device__ __forceinline__ f32x4 mfma16(bf16x8 a, bf16x8 b, f32x4 c) {
    return __builtin_amdgcn_mfma_f32_16x16x32_bf16(a, b, c, 0, 0, 0);
}
__device__ __forceinline__ f32x16 mfma32(bf16x8 a, bf16x8 b, f32x16 c) {
    return __builtin_amdgcn_mfma_f32_32x32x16_bf16(a, b, c, 0, 0, 0);
}
__device__ __forceinline__ u32 packbf(float lo, float hi) {
    union { __bf16 e[2]; u32 w; } u;
    u.e[0] = (__bf16)lo; u.e[1] = (__bf16)hi;
    return u.w;
}
__device__ __forceinline__ f32x16 zero16() {
    f32x16 z;
    #pragma unroll
    for (int i = 0; i < 16; i++) z[i] = 0.f;
    return z;
}

// ---- W fp32 -> bf16, FRAGMENT-NATIVE order for proj's mfma16 B-operand ----
// frag id = ks*12 + fn, ks = k-chunk of 32 (0..31), fn = n-tile (0..11).
// frag element (lane l, j): n = fn*16 + (l&15), k = ks*32 + (l>>4)*8 + j.
__global__ __launch_bounds__(256) void convert_w_kernel(
    const float* __restrict__ Wq, const float* __restrict__ Wk,
    const float* __restrict__ Wv, __bf16* __restrict__ wf)
{
    int e = (blockIdx.x * 256 + threadIdx.x) * 4;   // 192 blocks, bf16x4 each
    int frag = e >> 9;              // 0..383
    int wi = e & 511;
    int l = wi >> 3, j = wi & 7;    // j in {0,4}
    int ft = frag / 12, fn = frag - ft * 12;
    int n = fn * 16 + (l & 15);
    int k = ft * 32 + ((l >> 4) & 3) * 8 + j;
    const float* src = (n < 64 ? Wq : (n < 128 ? Wk : Wv))
                     + (size_t)(n & 63) * 1024 + k;
    float4 f = *(const float4*)src;
    bf16x4 h = {(__bf16)f.x, (__bf16)f.y, (__bf16)f.z, (__bf16)f.w};
    *(bf16x4*)(wf + e) = h;
}

// ------ QKV projection (M=16384,N=192,K=1024) + fused RoPE + q-prescale ------
// 1024 blocks x 16 rows, 4 waves (one 48-col N-group each). ONE staging barrier:
// x[16][1024] -> bf16 LDS (pad 1032), then a BARRIER-FREE main loop: per k-step
// each wave does 1 ds_read_b128 + 3 coalesced L2 W-frag loads + 3 MFMA. No
// inter-wave deps -> compiler pipelines loads freely. Epilogue: rope -> LDS
// scatter (fragment-native intra-tile offsets) -> coalesced run copy-out.
__global__ __launch_bounds__(256) void proj_kernel(
    const float* __restrict__ x, const __bf16* __restrict__ wf,
    __bf16* __restrict__ qfb, __bf16* __restrict__ kfb, __bf16* __restrict__ vfb)
{
    __shared__ __bf16 smem[16512];   // xs[16][1032] (33KB) ; stage[3][2048] reuse
    const int tid  = threadIdx.x;
    const int wave = tid >> 6, lane = tid & 63;
    const int l15 = lane & 15, l4 = lane >> 4;
    const size_t m0 = (size_t)blockIdx.x * 16;

    // ---- one-shot stage: x[16][1024] fp32 -> bf16 LDS ----
    {
        const int row = tid >> 4, c0 = (tid & 15) * 64;
        const float* src = x + (m0 + row) * 1024 + c0;
        __bf16* dst = smem + row * 1032 + c0;
        #pragma unroll
        for (int u = 0; u < 8; u++) {
            float4 f0 = *(const float4*)(src + u * 8);
            float4 f1 = *(const float4*)(src + u * 8 + 4);
            bf16x8 h = {(__bf16)f0.x, (__bf16)f0.y, (__bf16)f0.z, (__bf16)f0.w,
                        (__bf16)f1.x, (__bf16)f1.y, (__bf16)f1.z, (__bf16)f1.w};
            *(bf16x8*)(dst + u * 8) = h;
        }
    }
    __syncthreads();

    // ---- barrier-free main loop ----
    f32x4 acc[3];
    #pragma unroll
    for (int nf = 0; nf < 3; nf++) acc[nf] = (f32x4){0.f, 0.f, 0.f, 0.f};
    const __bf16* wfw = wf + (size_t)(wave * 3) * 512 + lane * 8;
    const __bf16* xls = smem + l15 * 1032 + l4 * 8;
    #pragma unroll 4
    for (int ks = 0; ks < 32; ks++) {
        bf16x8 af = *(const bf16x8*)(xls + ks * 32);
        const __bf16* wp = wfw + (size_t)(ks * 12) * 512;
        #pragma unroll
        for (int nf = 0; nf < 3; nf++) {
            bf16x8 bw = *(const bf16x8*)(wp + (size_t)nf * 512);
            acc[nf] = mfma16(af, bw, acc[nf]);
        }
    }
    __syncthreads();   // all xs reads done; smem reusable as stage

    // ---- epilogue: rope + scatter into stage at fragment-native offsets ----
    // C layout: col n = wave*48 + nf*16 + l15, row16 = l4*4 + r.
    const int tq0 = (int)(m0 & 4095);
    const int h16 = (int)((m0 >> 4) & 1);
    #pragma unroll
    for (int nf = 0; nf < 3; nf++) {
        int n = wave * 48 + nf * 16 + l15;
        #pragma unroll
        for (int r = 0; r < 4; r++) {
            int row16 = l4 * 4 + r;
            int row32 = h16 * 16 + row16;
            float val = acc[nf][r];
            float partner = __shfl_xor(val, 1);
            if (n < 128) {
                int i = (n & 63) >> 1;
                float ang = (float)(tq0 + row16)
                          * __builtin_exp2f((float)i * (-13.287712379549449f / 32.f));
                float sn, cs;
                __sincosf(ang, &sn, &cs);
                float res = (n & 1) ? (partner * sn + val * cs)
                                    : (val * cs - partner * sn);
                if (n < 64) {
                    res *= 0.180336884f;    // (1/8)*log2(e) folded into q
                    int d = n;
                    smem[(d >> 4) * 512 + (row32 + ((d >> 3) & 1) * 32) * 8 + (d & 7)]
                        = (__bf16)res;
                } else {
                    int d = n - 64;
                    int l31i = ((row32 >> 2) & 1) * 16 + ((row32 >> 4) & 1) * 8
                             + ((row32 >> 3) & 1) * 4 + (row32 & 3);   // pi^-1
                    smem[2048 + (d >> 4) * 512
                         + (l31i + ((d >> 3) & 1) * 32) * 8 + (d & 7)] = (__bf16)res;
                }
            } else {
                int d = n - 128;
                int cc = ((d >> 5) << 1) | ((row32 & 31) >> 4);
                smem[4096 + cc * 512
                     + ((d & 31) + ((row32 >> 3) & 1) * 32) * 8 + (row32 & 7)]
                    = (__bf16)val;
            }
        }
    }
    __syncthreads();

    // ---- coalesced run copy-out (half-tile) ----
    {
        const size_t bbase = (size_t)(m0 >> 12) * 262144;
        const size_t tbase = (size_t)((m0 & 4095) >> 5) * 2048;
        // Q: 8 runs of 128 elems
        {
            int rq = tid >> 5;
            int off = (rq >> 1) * 512 + (rq & 1) * 256 + h16 * 128 + (tid & 31) * 4;
            *(bf16x4*)(qfb + bbase + tbase + off) = *(const bf16x4*)&smem[off];
        }
        // K: 16 runs of 64 elems
        {
            int rk = tid >> 4;
            int off = (rk >> 2) * 512 + ((rk >> 1) & 1) * 256 + (rk & 1) * 128
                    + h16 * 64 + (tid & 15) * 4;
            *(bf16x4*)(kfb + bbase + tbase + off) = *(const bf16x4*)&smem[2048 + off];
        }
        // V: 2 runs of 512 elems
        {
            int part = tid >> 7;
            int off = part * 1024 + h16 * 512 + (tid & 127) * 4;
            *(bf16x4*)(vfb + bbase + tbase + off) = *(const bf16x4*)&smem[4096 + off];
        }
    }
}

// ---------------- causal flash attention, 1024-thread blocks ----------------
// 256 blocks = 1/CU. XCD-affine: b=(blk&7)>>1. Serial heavy (127-p) + light (p)
// halves -> balanced per CU. 16 waves = 16-way split-K over 32-row k-tiles.
// Swapped QK^T (lane -> one q col); fragment-native layouts make every load
// lane-consecutive (coalesced). pi permutation baked into kfb at store time;
// P->B-frag repack is a pure register rename. exp2 uses running base m.
__global__ __launch_bounds__(1024) void flash_kernel(
    const __bf16* __restrict__ qfb, const __bf16* __restrict__ kfb,
    const __bf16* __restrict__ vfb, float* __restrict__ out)
{
    __shared__ float ods[16][32][36];   // two-pass merge buffer (o0 then o1)
    __shared__ float mls[2][16][32];

    const int tid = threadIdx.x;
    const int wave = tid >> 6, lane = tid & 63;
    const int l31 = lane & 31, h = lane >> 5;
    const int xcd = blockIdx.x & 7;
    const int b = xcd >> 1;
    const int p = ((blockIdx.x >> 3) << 1) | (xcd & 1);   // 0..63 per batch

    const __bf16* qb_b = qfb + (size_t)b * 262144;
    const __bf16* kb_b = kfb + (size_t)b * 262144;
    const __bf16* vb_b = vfb + (size_t)b * 262144;

    #pragma unroll 1
    for (int half = 0; half < 2; half++) {
        const int jt = half ? p : 127 - p;
        const int q0 = jt * 32;
        const int qg = q0 + l31;

        // Q B-frags: coalesced tile load
        const __bf16* qp = qb_b + (size_t)jt * 2048 + lane * 8;
        bf16x8 qf[4];
        #pragma unroll
        for (int dc = 0; dc < 4; dc++) qf[dc] = *(const bf16x8*)(qp + dc * 512);

        float m = 16.f, l = 0.f;
        f32x16 o0 = zero16(), o1 = zero16();
        const int nt = jt + 1;   // 32-row k-tiles

        #pragma unroll 1
        for (int kt = wave; kt < nt; kt += 16) {
            const int kc0 = kt << 5;
            // K + V frags: coalesced tile loads
            const __bf16* kr = kb_b + (size_t)kt * 2048 + lane * 8;
            bf16x8 kf0 = *(const bf16x8*)(kr);
            bf16x8 kf1 = *(const bf16x8*)(kr + 512);
            bf16x8 kf2 = *(const bf16x8*)(kr + 1024);
            bf16x8 kf3 = *(const bf16x8*)(kr + 1536);
            const __bf16* vr = vb_b + (size_t)kt * 2048 + lane * 8;
            bf16x8 vf00 = *(const bf16x8*)(vr);          // d 0..31,  cg 0
            bf16x8 vf01 = *(const bf16x8*)(vr + 512);    // d 0..31,  cg 1
            bf16x8 vf10 = *(const bf16x8*)(vr + 1024);   // d 32..63, cg 0
            bf16x8 vf11 = *(const bf16x8*)(vr + 1536);   // d 32..63, cg 1
            f32x16 s = zero16();
            __builtin_amdgcn_s_setprio(1);
            s = mfma32(kf0, qf[0], s);
            s = mfma32(kf1, qf[1], s);
            s = mfma32(kf2, qf[2], s);
            s = mfma32(kf3, qf[3], s);
            __builtin_amdgcn_s_setprio(0);
            // causal mask: only the diagonal tile straddles
            if (kt == jt) {
                #pragma unroll
                for (int r = 0; r < 16; r++) {
                    int pioff = ((r >> 2) & 1) * 16 + 8 * h + (r >> 3) * 4 + (r & 3);
                    if (kc0 + pioff > qg) s[r] = -1e30f;
                }
            }
            // local max tree (defer check only; does NOT gate the exp)
            float tm[8];
            #pragma unroll
            for (int i = 0; i < 8; i++) tm[i] = fmaxf(s[2 * i], s[2 * i + 1]);
            #pragma unroll
            for (int i = 0; i < 4; i++) tm[i] = fmaxf(tm[i], tm[i + 4]);
            float tmax = fmaxf(fmaxf(tm[0], tm[1]), fmaxf(tm[2], tm[3]));
            // exp2 against running base m — no reduction wait on critical path
            float ts[4] = {0.f, 0.f, 0.f, 0.f};
            #pragma unroll
            for (int r = 0; r < 16; r++) {
                float e = __builtin_exp2f(s[r] - m);
                s[r] = e;
                ts[r & 3] += e;
            }
            float lsum = (ts[0] + ts[1]) + (ts[2] + ts[3]);
            // cross-half exchanges issued now, consumed after PV
            float lsum_p = __shfl_xor(lsum, 32);
            float tmax_p = __shfl_xor(tmax, 32);
            // P -> B-frags: pure register rename under pi (no shuffles)
            union { u32 w[4]; bf16x8 v; } pf[2];
            #pragma unroll
            for (int cg = 0; cg < 2; cg++) {
                pf[cg].w[0] = packbf(s[4 * cg + 0],  s[4 * cg + 1]);
                pf[cg].w[1] = packbf(s[4 * cg + 2],  s[4 * cg + 3]);
                pf[cg].w[2] = packbf(s[4 * cg + 8],  s[4 * cg + 9]);
                pf[cg].w[3] = packbf(s[4 * cg + 10], s[4 * cg + 11]);
            }
            // PV: O^T += V^T P^T
            __builtin_amdgcn_s_setprio(1);
            o0 = mfma32(vf00, pf[0].v, o0);
            o0 = mfma32(vf01, pf[1].v, o0);
            o1 = mfma32(vf10, pf[0].v, o1);
            o1 = mfma32(vf11, pf[1].v, o1);
            __builtin_amdgcn_s_setprio(0);
            // fold reductions; rescale AFTER accumulation (tile used base m)
            l += lsum + lsum_p;
            float tmx = fmaxf(tmax, tmax_p);
            if (!__all(tmx <= m + 8.f)) {
                const float mnew = fmaxf(m, tmx);
                const float alpha = __builtin_exp2f(m - mnew);
                m = mnew;
                l *= alpha;
                #pragma unroll
                for (int r = 0; r < 16; r++) { o0[r] *= alpha; o1[r] *= alpha; }
            }
        }

        // ---- two-pass 16-way merge; O^T C-layout col q=l31, row d=(r&3)+8*(r>>2)+4h
        const int q = tid >> 5, dcm = tid & 31;
        // pass A: d = 0..31 (o0)
        #pragma unroll
        for (int c2 = 0; c2 < 4; c2++) {
            f32x4 w0 = {o0[4 * c2], o0[4 * c2 + 1], o0[4 * c2 + 2], o0[4 * c2 + 3]};
            *(f32x4*)&ods[wave][l31][8 * c2 + 4 * h] = w0;
        }
        if (h == 0) {
            mls[0][wave][l31] = (wave < nt) ? m : -1e30f;   // empty splits: weight 0
            mls[1][wave][l31] = l;
        }
        __syncthreads();
        float M = -1e30f;
        #pragma unroll
        for (int s2 = 0; s2 < 16; s2++) M = fmaxf(M, mls[0][s2][q]);
        float w16[16], L = 0.f;
        #pragma unroll
        for (int s2 = 0; s2 < 16; s2++) {
            float ws = __builtin_exp2f(mls[0][s2][q] - M);
            w16[s2] = ws;
            L += ws * mls[1][s2][q];
        }
        const float invL = 1.f / L;
        float accA = 0.f;
        #pragma unroll
        for (int s2 = 0; s2 < 16; s2++) accA += w16[s2] * ods[s2][q][dcm];
        out[((size_t)b * T_LEN + q0 + q) * 64 + dcm] = accA * invL;
        __syncthreads();
        // pass B: d = 32..63 (o1)
        #pragma unroll
        for (int c2 = 0; c2 < 4; c2++) {
            f32x4 w1 = {o1[4 * c2], o1[4 * c2 + 1], o1[4 * c2 + 2], o1[4 * c2 + 3]};
            *(f32x4*)&ods[wave][l31][8 * c2 + 4 * h] = w1;
        }
        __syncthreads();
        float accB = 0.f;
        #pragma unroll
        for (int s2 = 0; s2 < 16; s2++) accB += w16[s2] * ods[s2][q][dcm];
        out[((size_t)b * T_LEN + q0 + q) * 64 + 32 + dcm] = accB * invL;
        __syncthreads();
    }
}

extern "C" void kernel_launch(void* const* d_in, const int* in_sizes, int n_in,
                              void* d_out, int out_size, void* d_ws, size_t ws_size,
                              hipStream_t stream)
{
    const float* x  = (const float*)d_in[0];
    const float* Wq = (const float*)d_in[1];
    const float* Wk = (const float*)d_in[2];
    const float* Wv = (const float*)d_in[3];
    float* out = (float*)d_out;

    __bf16* qfb = (__bf16*)d_ws;         // 2 MB, fragment-native (rope+prescale)
    __bf16* kfb = qfb + 1048576;         // 2 MB, fragment-native (rope, pi-permuted)
    __bf16* vfb = kfb + 1048576;         // 2 MB, fragment-native (PV operand order)
    __bf16* wf  = vfb + 1048576;         // 384 KB, fragment-native W

    convert_w_kernel<<<192, 256, 0, stream>>>(Wq, Wk, Wv, wf);
    proj_kernel<<<1024, 256, 0, stream>>>(x, wf, qfb, kfb, vfb);
    flash_kernel<<<256, 1024, 0, stream>>>(qfb, kfb, vfb, out);
}

// Round 16
// 54.241 us; speedup vs baseline: 1.0985x; 1.0985x over previous
//
#include <hip/hip_runtime.h>

typedef __bf16 bf16x8 __attribute__((ext_vector_type(8)));
typedef __bf16 bf16x4 __attribute__((ext_vector_type(4)));
typedef float f32x4 __attribute__((ext_vector_type(4)));
typedef float f32x16 __attribute__((ext_vector_type(16)));
typedef unsigned int u32;

#define T_LEN 4096

__device__ __forceinline__ f32x4 mfma16(bf16x8 a, bf16x8 b, f32x4 c) {
    return __builtin_amdgcn_mfma_f32_16x16x32_bf16(a, b, c, 0, 0, 0);
}
__device__ __forceinline__ f32x16 mfma32(bf16x8 a, bf16x8 b, f32x16 c) {
    return __builtin_amdgcn_mfma_f32_32x32x16_bf16(a, b, c, 0, 0, 0);
}
__device__ __forceinline__ u32 packbf(float lo, float hi) {
    union { __bf16 e[2]; u32 w; } u;
    u.e[0] = (__bf16)lo; u.e[1] = (__bf16)hi;
    return u.w;
}
__device__ __forceinline__ f32x16 zero16() {
    f32x16 z;
    #pragma unroll
    for (int i = 0; i < 16; i++) z[i] = 0.f;
    return z;
}

// ---------------- W fp32 -> bf16 (ws), row-major, vectorized ----------------
__global__ __launch_bounds__(256) void convert_w_kernel(
    const float* __restrict__ Wq, const float* __restrict__ Wk,
    const float* __restrict__ Wv, __bf16* __restrict__ wb)
{
    int i = blockIdx.x * 256 + threadIdx.x;      // 49152 threads, 4 elems each
    int m = i >> 14, off = (i & 16383) << 2;
    const float* s = (m == 0 ? Wq : (m == 1 ? Wk : Wv)) + off;
    float4 f = *(const float4*)s;
    bf16x4 h = { (__bf16)f.x, (__bf16)f.y, (__bf16)f.z, (__bf16)f.w };
    *(bf16x4*)(wb + (m << 16) + off) = h;
}

// ------ QKV projection (M=16384,N=192,K=1024) + fused RoPE + q-prescale ------
// r6-proven K-loop: 256 blocks x 64 rows, 8 waves (2M x 4N), W LDS double-
// buffer, reg-staged, one barrier per K-iteration. Epilogue (r13-proven):
// rope -> LDS scatter at fragment-native intra-tile offsets -> 6 coalesced
// bf16x4 stores per thread.
__global__ __launch_bounds__(512, 2) void proj_kernel(
    const float* __restrict__ x, const __bf16* __restrict__ wb,
    __bf16* __restrict__ qfb, __bf16* __restrict__ kfb, __bf16* __restrict__ vfb)
{
    __shared__ __bf16 smem[36864];   // xs[2][64][72] (9216) | wl[2][192][72] (27648)
    __bf16 (*xs)[64][72]  = (__bf16(*)[64][72])smem;
    __bf16 (*wl)[192][72] = (__bf16(*)[192][72])(smem + 9216);
    __bf16* stage = smem;            // [2][3][2048] = 12288, reused after loop

    const int tid  = threadIdx.x;
    const int wave = tid >> 6, lane = tid & 63;
    const int l15 = lane & 15, l4 = lane >> 4;
    const int wm = wave >> 2, wn = wave & 3;     // 2 M-halves x 4 N-groups
    const size_t m0 = (size_t)blockIdx.x * 64;
    const int srow = tid >> 3, scp = (tid & 7) * 8;

    f32x4 acc[2][3];
    #pragma unroll
    for (int a = 0; a < 2; a++)
        #pragma unroll
        for (int bn = 0; bn < 3; bn++) acc[a][bn] = (f32x4){0.f, 0.f, 0.f, 0.f};

    const float* xsrc = x + (m0 + srow) * 1024 + scp;

    float4 rx0, rx1;
    bf16x8 rw[3];

    // prologue: tile 0 -> regs -> LDS buf 0
    rx0 = *(const float4*)(xsrc);
    rx1 = *(const float4*)(xsrc + 4);
    #pragma unroll
    for (int j = 0; j < 3; j++)
        rw[j] = *(const bf16x8*)(wb + (size_t)(srow + j * 64) * 1024 + scp);
    {
        bf16x8 h = {(__bf16)rx0.x, (__bf16)rx0.y, (__bf16)rx0.z, (__bf16)rx0.w,
                    (__bf16)rx1.x, (__bf16)rx1.y, (__bf16)rx1.z, (__bf16)rx1.w};
        *(bf16x8*)&xs[0][srow][scp] = h;
        #pragma unroll
        for (int j = 0; j < 3; j++)
            *(bf16x8*)&wl[0][srow + j * 64][scp] = rw[j];
    }
    __syncthreads();

    for (int t = 0; t < 16; t++) {
        const int cur = t & 1;
        if (t < 15) {   // issue next tile's loads early (overlap with compute)
            const int k0 = (t + 1) * 64;
            rx0 = *(const float4*)(xsrc + k0);
            rx1 = *(const float4*)(xsrc + k0 + 4);
            #pragma unroll
            for (int j = 0; j < 3; j++)
                rw[j] = *(const bf16x8*)(wb + (size_t)(srow + j * 64) * 1024 + k0 + scp);
        }
        // compute tile t from LDS[cur]
        bf16x8 af[2][2], bfr[3][2];
        #pragma unroll
        for (int mf = 0; mf < 2; mf++)
            #pragma unroll
            for (int c = 0; c < 2; c++)
                af[mf][c] = *(const bf16x8*)&xs[cur][wm * 32 + mf * 16 + l15][c * 32 + l4 * 8];
        #pragma unroll
        for (int nf = 0; nf < 3; nf++)
            #pragma unroll
            for (int c = 0; c < 2; c++)
                bfr[nf][c] = *(const bf16x8*)&wl[cur][wn * 48 + nf * 16 + l15][c * 32 + l4 * 8];
        #pragma unroll
        for (int mf = 0; mf < 2; mf++)
            #pragma unroll
            for (int nf = 0; nf < 3; nf++)
                #pragma unroll
                for (int c = 0; c < 2; c++)
                    acc[mf][nf] = mfma16(af[mf][c], bfr[nf][c], acc[mf][nf]);
        if (t < 15) {   // stage tile t+1 into the other buffer
            bf16x8 h = {(__bf16)rx0.x, (__bf16)rx0.y, (__bf16)rx0.z, (__bf16)rx0.w,
                        (__bf16)rx1.x, (__bf16)rx1.y, (__bf16)rx1.z, (__bf16)rx1.w};
            *(bf16x8*)&xs[cur ^ 1][srow][scp] = h;
            #pragma unroll
            for (int j = 0; j < 3; j++)
                *(bf16x8*)&wl[cur ^ 1][srow + j * 64][scp] = rw[j];
        }
        __syncthreads();
    }
    // loop-final barrier passed: all LDS reads done; smem reusable as stage.

    // epilogue: C layout col = l15 (n), row64 = wm*32 + mf*16 + l4*4 + r;
    // rope fused for q,k; q pre-scaled by (1/8)*log2(e); scatter into LDS
    // stage[tile][out][2048], then coalesced copy-out.
    const int tq0 = (int)(m0 & 4095);   // 64-aligned
    #pragma unroll
    for (int nf = 0; nf < 3; nf++) {
        int n = wn * 48 + nf * 16 + l15;
        #pragma unroll
        for (int mf = 0; mf < 2; mf++) {
            #pragma unroll
            for (int r = 0; r < 4; r++) {
                int row64 = wm * 32 + mf * 16 + l4 * 4 + r;
                int tile = row64 >> 5, rr = row64 & 31;
                int tb = tile * 6144;
                float val = acc[mf][nf][r];
                float partner = __shfl_xor(val, 1);
                if (n < 128) {
                    int i = (n & 63) >> 1;
                    float ang = (float)(tq0 + row64)
                              * __builtin_exp2f((float)i * (-13.287712379549449f / 32.f));
                    float sn, cs;
                    __sincosf(ang, &sn, &cs);
                    float res = (n & 1) ? (partner * sn + val * cs)
                                        : (val * cs - partner * sn);
                    if (n < 64) {
                        res *= 0.180336884f;    // (1/8)*log2(e) folded into q
                        int d = n;
                        stage[tb + (d >> 4) * 512
                              + (rr + ((d >> 3) & 1) * 32) * 8 + (d & 7)] = (__bf16)res;
                    } else {
                        int d = n - 64;
                        int l31i = ((rr >> 2) & 1) * 16 + ((rr >> 4) & 1) * 8
                                 + ((rr >> 3) & 1) * 4 + (rr & 3);   // pi^-1
                        stage[tb + 2048 + (d >> 4) * 512
                              + (l31i + ((d >> 3) & 1) * 32) * 8 + (d & 7)] = (__bf16)res;
                    }
                } else {
                    int d = n - 128;
                    int cc = ((d >> 5) << 1) | (rr >> 4);
                    stage[tb + 4096 + cc * 512
                          + ((d & 31) + ((rr >> 3) & 1) * 32) * 8 + (rr & 7)]
                        = (__bf16)val;
                }
            }
        }
    }
    __syncthreads();
    {
        const size_t bbase = (size_t)(m0 >> 12) * 262144;
        const size_t tbase = (size_t)((m0 & 4095) >> 5) * 2048;   // first 32-row tile
        #pragma unroll
        for (int tile = 0; tile < 2; tile++) {
            const int tb = tile * 6144;
            const size_t go = bbase + tbase + (size_t)tile * 2048 + tid * 4;
            bf16x4 q4 = *(const bf16x4*)&stage[tb + tid * 4];
            bf16x4 k4 = *(const bf16x4*)&stage[tb + 2048 + tid * 4];
            bf16x4 v4 = *(const bf16x4*)&stage[tb + 4096 + tid * 4];
            *(bf16x4*)(qfb + go) = q4;
            *(bf16x4*)(kfb + go) = k4;
            *(bf16x4*)(vfb + go) = v4;
        }
    }
}

// ---------------- causal flash attention, 1024-thread blocks ----------------
// 256 blocks = 1/CU. XCD-affine: b=(blk&7)>>1. Serial heavy (127-p) + light (p)
// halves -> balanced per CU. 16 waves = 16-way split-K over 32-row k-tiles.
// Swapped QK^T (lane -> one q col); fragment-native layouts make every load
// lane-consecutive (coalesced). pi permutation baked into kfb at store time;
// P->B-frag repack is a pure register rename. exp2 uses running base m.
__global__ __launch_bounds__(1024) void flash_kernel(
    const __bf16* __restrict__ qfb, const __bf16* __restrict__ kfb,
    const __bf16* __restrict__ vfb, float* __restrict__ out)
{
    __shared__ float ods[16][32][36];   // two-pass merge buffer (o0 then o1)
    __shared__ float mls[2][16][32];

    const int tid = threadIdx.x;
    const int wave = tid >> 6, lane = tid & 63;
    const int l31 = lane & 31, h = lane >> 5;
    const int xcd = blockIdx.x & 7;
    const int b = xcd >> 1;
    const int p = ((blockIdx.x >> 3) << 1) | (xcd & 1);   // 0..63 per batch

    const __bf16* qb_b = qfb + (size_t)b * 262144;
    const __bf16* kb_b = kfb + (size_t)b * 262144;
    const __bf16* vb_b = vfb + (size_t)b * 262144;

    #pragma unroll 1
    for (int half = 0; half < 2; half++) {
        const int jt = half ? p : 127 - p;
        const int q0 = jt * 32;
        const int qg = q0 + l31;

        // Q B-frags: coalesced tile load
        const __bf16* qp = qb_b + (size_t)jt * 2048 + lane * 8;
        bf16x8 qf[4];
        #pragma unroll
        for (int dc = 0; dc < 4; dc++) qf[dc] = *(const bf16x8*)(qp + dc * 512);

        float m = 16.f, l = 0.f;
        f32x16 o0 = zero16(), o1 = zero16();
        const int nt = jt + 1;   // 32-row k-tiles

        #pragma unroll 1
        for (int kt = wave; kt < nt; kt += 16) {
            const int kc0 = kt << 5;
            // K + V frags: coalesced tile loads
            const __bf16* kr = kb_b + (size_t)kt * 2048 + lane * 8;
            bf16x8 kf0 = *(const bf16x8*)(kr);
            bf16x8 kf1 = *(const bf16x8*)(kr + 512);
            bf16x8 kf2 = *(const bf16x8*)(kr + 1024);
            bf16x8 kf3 = *(const bf16x8*)(kr + 1536);
            const __bf16* vr = vb_b + (size_t)kt * 2048 + lane * 8;
            bf16x8 vf00 = *(const bf16x8*)(vr);          // d 0..31,  cg 0
            bf16x8 vf01 = *(const bf16x8*)(vr + 512);    // d 0..31,  cg 1
            bf16x8 vf10 = *(const bf16x8*)(vr + 1024);   // d 32..63, cg 0
            bf16x8 vf11 = *(const bf16x8*)(vr + 1536);   // d 32..63, cg 1
            f32x16 s = zero16();
            __builtin_amdgcn_s_setprio(1);
            s = mfma32(kf0, qf[0], s);
            s = mfma32(kf1, qf[1], s);
            s = mfma32(kf2, qf[2], s);
            s = mfma32(kf3, qf[3], s);
            __builtin_amdgcn_s_setprio(0);
            // causal mask: only the diagonal tile straddles
            if (kt == jt) {
                #pragma unroll
                for (int r = 0; r < 16; r++) {
                    int pioff = ((r >> 2) & 1) * 16 + 8 * h + (r >> 3) * 4 + (r & 3);
                    if (kc0 + pioff > qg) s[r] = -1e30f;
                }
            }
            // local max tree (defer check only; does NOT gate the exp)
            float tm[8];
            #pragma unroll
            for (int i = 0; i < 8; i++) tm[i] = fmaxf(s[2 * i], s[2 * i + 1]);
            #pragma unroll
            for (int i = 0; i < 4; i++) tm[i] = fmaxf(tm[i], tm[i + 4]);
            float tmax = fmaxf(fmaxf(tm[0], tm[1]), fmaxf(tm[2], tm[3]));
            // exp2 against running base m — no reduction wait on critical path
            float ts[4] = {0.f, 0.f, 0.f, 0.f};
            #pragma unroll
            for (int r = 0; r < 16; r++) {
                float e = __builtin_exp2f(s[r] - m);
                s[r] = e;
                ts[r & 3] += e;
            }
            float lsum = (ts[0] + ts[1]) + (ts[2] + ts[3]);
            // cross-half exchanges issued now, consumed after PV
            float lsum_p = __shfl_xor(lsum, 32);
            float tmax_p = __shfl_xor(tmax, 32);
            // P -> B-frags: pure register rename under pi (no shuffles)
            union { u32 w[4]; bf16x8 v; } pf[2];
            #pragma unroll
            for (int cg = 0; cg < 2; cg++) {
                pf[cg].w[0] = packbf(s[4 * cg + 0],  s[4 * cg + 1]);
                pf[cg].w[1] = packbf(s[4 * cg + 2],  s[4 * cg + 3]);
                pf[cg].w[2] = packbf(s[4 * cg + 8],  s[4 * cg + 9]);
                pf[cg].w[3] = packbf(s[4 * cg + 10], s[4 * cg + 11]);
            }
            // PV: O^T += V^T P^T
            __builtin_amdgcn_s_setprio(1);
            o0 = mfma32(vf00, pf[0].v, o0);
            o0 = mfma32(vf01, pf[1].v, o0);
            o1 = mfma32(vf10, pf[0].v, o1);
            o1 = mfma32(vf11, pf[1].v, o1);
            __builtin_amdgcn_s_setprio(0);
            // fold reductions; rescale AFTER accumulation (tile used base m)
            l += lsum + lsum_p;
            float tmx = fmaxf(tmax, tmax_p);
            if (!__all(tmx <= m + 8.f)) {
                const float mnew = fmaxf(m, tmx);
                const float alpha = __builtin_exp2f(m - mnew);
                m = mnew;
                l *= alpha;
                #pragma unroll
                for (int r = 0; r < 16; r++) { o0[r] *= alpha; o1[r] *= alpha; }
            }
        }

        // ---- two-pass 16-way merge; O^T C-layout col q=l31, row d=(r&3)+8*(r>>2)+4h
        const int q = tid >> 5, dcm = tid & 31;
        // pass A: d = 0..31 (o0)
        #pragma unroll
        for (int c2 = 0; c2 < 4; c2++) {
            f32x4 w0 = {o0[4 * c2], o0[4 * c2 + 1], o0[4 * c2 + 2], o0[4 * c2 + 3]};
            *(f32x4*)&ods[wave][l31][8 * c2 + 4 * h] = w0;
        }
        if (h == 0) {
            mls[0][wave][l31] = (wave < nt) ? m : -1e30f;   // empty splits: weight 0
            mls[1][wave][l31] = l;
        }
        __syncthreads();
        float M = -1e30f;
        #pragma unroll
        for (int s2 = 0; s2 < 16; s2++) M = fmaxf(M, mls[0][s2][q]);
        float w16[16], L = 0.f;
        #pragma unroll
        for (int s2 = 0; s2 < 16; s2++) {
            float ws = __builtin_exp2f(mls[0][s2][q] - M);
            w16[s2] = ws;
            L += ws * mls[1][s2][q];
        }
        const float invL = 1.f / L;
        float accA = 0.f;
        #pragma unroll
        for (int s2 = 0; s2 < 16; s2++) accA += w16[s2] * ods[s2][q][dcm];
        out[((size_t)b * T_LEN + q0 + q) * 64 + dcm] = accA * invL;
        __syncthreads();
        // pass B: d = 32..63 (o1)
        #pragma unroll
        for (int c2 = 0; c2 < 4; c2++) {
            f32x4 w1 = {o1[4 * c2], o1[4 * c2 + 1], o1[4 * c2 + 2], o1[4 * c2 + 3]};
            *(f32x4*)&ods[wave][l31][8 * c2 + 4 * h] = w1;
        }
        __syncthreads();
        float accB = 0.f;
        #pragma unroll
        for (int s2 = 0; s2 < 16; s2++) accB += w16[s2] * ods[s2][q][dcm];
        out[((size_t)b * T_LEN + q0 + q) * 64 + 32 + dcm] = accB * invL;
        __syncthreads();
    }
}

extern "C" void kernel_launch(void* const* d_in, const int* in_sizes, int n_in,
                              void* d_out, int out_size, void* d_ws, size_t ws_size,
                              hipStream_t stream)
{
    const float* x  = (const float*)d_in[0];
    const float* Wq = (const float*)d_in[1];
    const float* Wk = (const float*)d_in[2];
    const float* Wv = (const float*)d_in[3];
    float* out = (float*)d_out;

    __bf16* qfb = (__bf16*)d_ws;         // 2 MB, fragment-native (rope+prescale)
    __bf16* kfb = qfb + 1048576;         // 2 MB, fragment-native (rope, pi-permuted)
    __bf16* vfb = kfb + 1048576;         // 2 MB, fragment-native (PV operand order)
    __bf16* wb  = vfb + 1048576;         // 384 KB, row-major W

    convert_w_kernel<<<192, 256, 0, stream>>>(Wq, Wk, Wv, wb);
    proj_kernel<<<256, 512, 0, stream>>>(x, wb, qfb, kfb, vfb);
    flash_kernel<<<256, 1024, 0, stream>>>(qfb, kfb, vfb, out);
}